// Round 15
// baseline (142.008 us; speedup 1.0000x reference)
//
#include <hip/hip_runtime.h>

#define TB 256
#define NA_G (32 * 12 * 1024)   // 16B-groups in A tiles
#define NB_G (64 * 12 * 1024)   // 16B-groups in B tiles
#define NEED_T ((size_t)(NA_G + NB_G) * 16)          // 18.87 MB bf16 tiles

typedef __bf16 bf16x8 __attribute__((ext_vector_type(8)));
typedef float f32x4 __attribute__((ext_vector_type(4)));
typedef unsigned u32x4 __attribute__((ext_vector_type(4)));
typedef unsigned u32x2 __attribute__((ext_vector_type(2)));
typedef unsigned long long ull;

__device__ __forceinline__ unsigned pack2bf(float a, float b) {
  unsigned ua = __float_as_uint(a), ub = __float_as_uint(b);
  ua = (ua + 0x7fffu + ((ua >> 16) & 1u)) >> 16;   // RNE f32->bf16
  ub = (ub + 0x7fffu + ((ub >> 16) & 1u)) >> 16;
  return ua | (ub << 16);
}
__device__ __forceinline__ float bf2f(unsigned bits) {
  return __uint_as_float(bits << 16);
}
__device__ __forceinline__ void gll16(const void* g, void* l) {
  __builtin_amdgcn_global_load_lds(
      (const __attribute__((address_space(1))) unsigned*)g,
      (__attribute__((address_space(3))) unsigned*)l, 16, 0, 0);
}

// Pre-convert f32 -> bf16 into XOR-swizzled 128x64 tiles (LDS-image layout)
__global__ __launch_bounds__(256) void convert_pack(
    const float* __restrict__ q, const float* __restrict__ p,
    unsigned char* __restrict__ qt, unsigned char* __restrict__ pt) {
  int g = blockIdx.x * 256 + threadIdx.x;
  const float* src;
  unsigned char* dst;
  if (g < NA_G) { src = q; dst = qt; }
  else { g -= NA_G; src = p; dst = pt; }
  int tile = g >> 10;
  int o = (g & 1023) * 16;
  int row = o >> 7;
  int colb = (o & 127) ^ ((row & 7) << 4);
  int rb = tile / 12, kt = tile - rb * 12;
  const float* s = src + ((size_t)(rb * 128 + row)) * 768 + kt * 64 + (colb >> 1);
  float4 a = ((const float4*)s)[0];
  float4 b = ((const float4*)s)[1];
  uint4 w;
  w.x = pack2bf(a.x, a.y); w.y = pack2bf(a.z, a.w);
  w.z = pack2bf(b.x, b.y); w.w = pack2bf(b.z, b.w);
  *(uint4*)(dst + (size_t)tile * 16384 + o) = w;
}

// ===== fused: GEMM -> bf16 LDS handoff -> 2-pass fixed-point hist select =====
// All selection atomics are INT (float LDS atomicAdd = CAS loop, R10/R11 bug).
// Fixed-point trick: q = (x-mn)*65535/(mx-mn); bin = q>>8; atomicAdd(q) gives
// per-bin value sums with native int atomics -> top/bottom sums come straight
// from the (count,fixsum) scan + binFix*R/c tail. NO third traversal.
template <int PATH>
__global__ __launch_bounds__(TB, 4) void dpr_fused(
    const float* __restrict__ q_emb, const float* __restrict__ p_emb,
    const void* __restrict__ qmr, const void* __restrict__ pmr,
    const float* __restrict__ alpha_raw, const float* __restrict__ beta_raw,
    const unsigned char* __restrict__ qt, const unsigned char* __restrict__ pt,
    float* __restrict__ out) {
  __shared__ __align__(16) char arena[32768];     // GEMM: Al|Bl ; then 4x8KB S quadrants
  __shared__ unsigned harena[4][528];             // per wave: cnt[257] | pad | fix[257]
  unsigned short* Al = (unsigned short*)arena;
  unsigned short* Bl = (unsigned short*)(arena + 16384);

  const int tid = threadIdx.x, lane = tid & 63, wid = tid >> 6;
  // XCD-clustered bid map: 8 regions of 16x16 block-tiles
  int g = blockIdx.x;
  int rg = g & 7, w = g >> 3;
  const int blockB = (rg >> 2) * 16 + (w & 15);
  const int blockP = (rg & 3) * 16 + (w >> 4);
  const int lr = lane & 15, lg = lane >> 4;
  const int db = wid >> 1, dp = wid & 1;

  // ---- per-wave masks (dtype sniffed) ----
  bool m32 = true;
  {
    const unsigned* qm32 = (const unsigned*)qmr;
    #pragma unroll
    for (int i = 0; i < 8; ++i) m32 = m32 && (qm32[i] <= 1u);
  }
  int qrow = (blockB * 2 + db) * 64 + lane;
  int pcolg = (blockP * 2 + dp) * 64 + lane;
  bool qvb = m32 ? (((const int*)qmr)[qrow] != 0) : (((const unsigned char*)qmr)[qrow] != 0);
  bool pvb = m32 ? (((const int*)pmr)[pcolg] != 0) : (((const unsigned char*)pmr)[pcolg] != 0);
  ull qb = __ballot(qvb);
  ull pb = __ballot(pvb);
  const int n_pair = __popcll(qb) * __popcll(pb);

  // ---- GEMM: 128x128 block tile, each wave owns one 64x64 pair ----
  f32x4 acc[4][4];
  #pragma unroll
  for (int m = 0; m < 4; ++m)
    #pragma unroll
    for (int n = 0; n < 4; ++n)
      acc[m][n] = f32x4{0.f, 0.f, 0.f, 0.f};

  const float* Abase = q_emb + (size_t)(blockB * 128) * 768;
  const float* Bbase = p_emb + (size_t)(blockP * 128) * 768;

  for (int kt = 0; kt < 12; ++kt) {
    if (PATH == 1) {
      const unsigned char* qtile = qt + ((size_t)(blockB * 12 + kt)) * 16384;
      const unsigned char* ptile = pt + ((size_t)(blockP * 12 + kt)) * 16384;
      #pragma unroll
      for (int c2 = 0; c2 < 4; ++c2) {
        int chunk = wid * 4 + c2;
        gll16(qtile + chunk * 1024 + lane * 16, (char*)Al + chunk * 1024);
        gll16(ptile + chunk * 1024 + lane * 16, (char*)Bl + chunk * 1024);
      }
    } else {
      const int k0 = kt * 64;
      #pragma unroll
      for (int it = 0; it < 4; ++it) {
        int gg = tid + 256 * it;
        int row = gg >> 3;
        int col = (gg & 7) * 8;
        int off = (row * 128 + col * 2) ^ ((row & 7) << 4);
        const float4* sA = (const float4*)(Abase + (size_t)row * 768 + k0 + col);
        float4 a0 = sA[0], a1 = sA[1];
        uint4 wv;
        wv.x = pack2bf(a0.x, a0.y); wv.y = pack2bf(a0.z, a0.w);
        wv.z = pack2bf(a1.x, a1.y); wv.w = pack2bf(a1.z, a1.w);
        *(uint4*)((char*)Al + off) = wv;
        const float4* sB = (const float4*)(Bbase + (size_t)row * 768 + k0 + col);
        float4 b0 = sB[0], b1 = sB[1];
        wv.x = pack2bf(b0.x, b0.y); wv.y = pack2bf(b0.z, b0.w);
        wv.z = pack2bf(b1.x, b1.y); wv.w = pack2bf(b1.z, b1.w);
        *(uint4*)((char*)Bl + off) = wv;
      }
    }
    __syncthreads();
    #pragma unroll
    for (int ks = 0; ks < 2; ++ks) {
      bf16x8 af[4], bfr[4];
      #pragma unroll
      for (int m = 0; m < 4; ++m) {
        int row = db * 64 + m * 16 + lr;
        int off = (row * 128 + ks * 64 + lg * 16) ^ ((row & 7) << 4);
        af[m] = *(const bf16x8*)((const char*)Al + off);
      }
      #pragma unroll
      for (int n = 0; n < 4; ++n) {
        int row = dp * 64 + n * 16 + lr;
        int off = (row * 128 + ks * 64 + lg * 16) ^ ((row & 7) << 4);
        bfr[n] = *(const bf16x8*)((const char*)Bl + off);
      }
      #pragma unroll
      for (int m = 0; m < 4; ++m)
        #pragma unroll
        for (int n = 0; n < 4; ++n)
          acc[m][n] = __builtin_amdgcn_mfma_f32_16x16x32_bf16(af[m], bfr[n], acc[m][n], 0, 0, 0);
    }
    __syncthreads();   // final barrier also fences arena reuse below
  }

  const int outIdx = (blockB * 2 + db) * 128 + (blockP * 2 + dp);
  if (n_pair == 0) {
    if (lane == 0) out[outIdx] = -1e9f;
    return;
  }

  // ---- handoff: pack acc -> wave-private 8KB LDS quadrant ----
  // layout S[c*64 + r] bf16, c = n*16+lr (p-col), r = m*16+lg*4+j (q-row)
  char* Sq = arena + wid * 8192;
  #pragma unroll
  for (int m = 0; m < 4; ++m)
    #pragma unroll
    for (int n = 0; n < 4; ++n) {
      int row = n * 16 + lr;
      int byte = row * 128 + m * 32 + lg * 8;
      int swz = byte ^ ((row & 7) << 4);
      u32x2 wv;
      wv.x = pack2bf(acc[m][n][0], acc[m][n][1]);
      wv.y = pack2bf(acc[m][n][2], acc[m][n][3]);
      *(u32x2*)(Sq + swz) = wv;
    }

  // read back 64 values/lane (same-wave LDS ops are in-order; no barrier)
  u32x4 vv[8];
  #pragma unroll
  for (int t = 0; t < 8; ++t) {
    int base = t * 1024 + lane * 16;
    vv[t] = *(const u32x4*)(Sq + (base ^ ((lane >> 3) << 4)));
  }

  // per-lane 64-bit validity mask: bit (t*8+jj)
  const unsigned qm8 = (unsigned)((qb >> ((lane & 7) * 8)) & 0xFFull);
  unsigned pm8 = 0;
  #pragma unroll
  for (int t = 0; t < 8; ++t)
    pm8 |= (unsigned)((pb >> (t * 8 + (lane >> 3))) & 1ull) << t;
  unsigned vlo = 0, vhi = 0;
  #pragma unroll
  for (int t = 0; t < 4; ++t)
    vlo |= (((pm8 >> t) & 1u) ? qm8 : 0u) << (8 * t);
  #pragma unroll
  for (int t = 4; t < 8; ++t)
    vhi |= (((pm8 >> t) & 1u) ? qm8 : 0u) << (8 * (t - 4));

  int ksel = 4 * n_pair / 10; if (ksel < 1) ksel = 1;
  int lsel = 2 * n_pair / 10; if (lsel < 1) lsel = 1;

  unsigned* c1 = &harena[wid][0];     // cnt[257]
  unsigned* f1 = &harena[wid][260];   // fix[257] (16B-aligned: 260*4=1040)

  // Pass A: masked min / max (registers + shfl). No tsum needed here.
  float mn = INFINITY, mx = -INFINITY;
  #pragma unroll
  for (int t = 0; t < 8; ++t)
    #pragma unroll
    for (int jj = 0; jj < 8; ++jj) {
      unsigned u = vv[t][jj >> 1];
      unsigned bits = (jj & 1) ? (u >> 16) : (u & 0xFFFFu);
      const int eidx = t * 8 + jj;
      unsigned vb = ((eidx < 32 ? vlo : vhi) >> (eidx & 31)) & 1u;
      float x = bf2f(bits);
      mn = fminf(mn, vb ? x : INFINITY);
      mx = fmaxf(mx, vb ? x : -INFINITY);
    }
  #pragma unroll
  for (int off = 1; off < 64; off <<= 1) {
    mn = fminf(mn, __shfl_xor(mn, off));
    mx = fmaxf(mx, __shfl_xor(mx, off));
  }

  float tsum, topS, botS;
  if (!(mx > mn)) {
    tsum = (float)n_pair * mn;        // all valid values identical
    topS = (float)ksel * mn;
    botS = (float)lsel * mn;
  } else {
    const float sc16 = 65535.0f / (mx - mn);
    const float inv16 = (mx - mn) * (1.0f / 65535.0f);

    // zero cnt+fix (incl. dump bin 256); same-wave in-order
    ((uint4*)c1)[lane] = uint4{0u, 0u, 0u, 0u};
    ((uint4*)f1)[lane] = uint4{0u, 0u, 0u, 0u};
    if (lane == 0) { c1[256] = 0u; f1[256] = 0u; }

    // Pass B: unconditional atomics; invalid elems -> dump bin 256.
    #pragma unroll
    for (int t = 0; t < 8; ++t)
      #pragma unroll
      for (int jj = 0; jj < 8; ++jj) {
        unsigned u = vv[t][jj >> 1];
        unsigned bits = (jj & 1) ? (u >> 16) : (u & 0xFFFFu);
        const int eidx = t * 8 + jj;
        unsigned vb = ((eidx < 32 ? vlo : vhi) >> (eidx & 31)) & 1u;
        float x = bf2f(bits);
        int q = (int)((x - mn) * sc16);
        q = q < 0 ? 0 : (q > 65535 ? 65535 : q);
        int bn = vb ? (q >> 8) : 256;
        atomicAdd(&c1[bn], 1u);
        atomicAdd(&f1[bn], (unsigned)q);
      }

    // scan: lane owns bins [lane*4, lane*4+4) of cnt+fix (dump bin excluded)
    uint4 cq = ((const uint4*)c1)[lane];
    uint4 fq = ((const uint4*)f1)[lane];
    const unsigned cl0 = cq.x, cl1 = cq.y, cl2 = cq.z, cl3 = cq.w;
    const unsigned fl0 = fq.x, fl1 = fq.y, fl2 = fq.z, fl3 = fq.w;
    const unsigned lc = cl0 + cl1 + cl2 + cl3;
    const unsigned lf = fl0 + fl1 + fl2 + fl3;
    unsigned runC = lc, runF = lf;
    #pragma unroll
    for (int off = 1; off < 64; off <<= 1) {
      unsigned o = __shfl_down(runC, off);
      unsigned of = __shfl_down(runF, off);
      if (lane + off < 64) { runC += o; runF += of; }
    }
    const unsigned totC = __shfl(runC, 0);
    const unsigned totF = __shfl(runF, 0);
    tsum = (float)totF * inv16 + (float)totC * mn;   // totC == n_pair

    // top locate (suffix: high bins first), carrying fix-sum-above
    unsigned aboveC = runC - lc, aboveF = runF - lf;
    bool fT = ((unsigned)ksel > aboveC) && ((unsigned)ksel <= runC);
    int sbT_ = 0, RT_ = 0; unsigned saF_ = 0u;
    if (fT) {
      unsigned a = aboveC, af = aboveF;
      if ((unsigned)ksel <= a + cl3) { sbT_ = 3; RT_ = (int)((unsigned)ksel - a); saF_ = af; }
      else { a += cl3; af += fl3;
      if ((unsigned)ksel <= a + cl2) { sbT_ = 2; RT_ = (int)((unsigned)ksel - a); saF_ = af; }
      else { a += cl2; af += fl2;
      if ((unsigned)ksel <= a + cl1) { sbT_ = 1; RT_ = (int)((unsigned)ksel - a); saF_ = af; }
      else { a += cl1; af += fl1; sbT_ = 0; RT_ = (int)((unsigned)ksel - a); saF_ = af; } } }
      sbT_ += lane * 4;
    }
    ull fmT = __ballot(fT);
    int srcT = fmT ? (int)__builtin_ctzll(fmT) : 0;
    const int sbT = __shfl(sbT_, srcT);
    const int RT = __shfl(RT_, srcT);
    const unsigned saFT = __shfl(saF_, srcT);

    // bottom locate (prefix: low bins first), carrying fix-sum-below
    unsigned belowC = totC - runC, belowF = totF - runF;
    bool fB = ((unsigned)lsel > belowC) && ((unsigned)lsel <= belowC + lc);
    int sbB_ = 0, RB_ = 0; unsigned sbF_ = 0u;
    if (fB) {
      unsigned a = belowC, af = belowF;
      if ((unsigned)lsel <= a + cl0) { sbB_ = 0; RB_ = (int)((unsigned)lsel - a); sbF_ = af; }
      else { a += cl0; af += fl0;
      if ((unsigned)lsel <= a + cl1) { sbB_ = 1; RB_ = (int)((unsigned)lsel - a); sbF_ = af; }
      else { a += cl1; af += fl1;
      if ((unsigned)lsel <= a + cl2) { sbB_ = 2; RB_ = (int)((unsigned)lsel - a); sbF_ = af; }
      else { a += cl2; af += fl2; sbB_ = 3; RB_ = (int)((unsigned)lsel - a); sbF_ = af; } } }
      sbB_ += lane * 4;
    }
    ull fmB = __ballot(fB);
    int srcB = fmB ? (int)__builtin_ctzll(fmB) : 0;
    const int sbB = __shfl(sbB_, srcB);
    const int RB = __shfl(RB_, srcB);
    const unsigned sbFB = __shfl(sbF_, srcB);

    // rank-bin count+fix (uniform-address broadcast reads)
    const unsigned cT = c1[sbT], bFixT = f1[sbT];
    const unsigned cB = c1[sbB], bFixB = f1[sbB];

    // tail = bin fix-mean * rank-in-bin; convert fix -> value domain
    float topFix = (float)saFT + (float)bFixT * ((float)RT / (float)cT);
    float botFix = (float)sbFB + (float)bFixB * ((float)RB / (float)cB);
    topS = topFix * inv16 + (float)ksel * mn;
    botS = botFix * inv16 + (float)lsel * mn;
  }

  if (lane == 0) {
    float alpha = log1pf(expf(alpha_raw[0]));
    float beta = log1pf(expf(beta_raw[0]));
    float total_mean = tsum / (float)n_pair;
    float top_mean = topS / (float)ksel;
    float bm = fmaxf(0.0f, -(botS / (float)lsel));
    out[outIdx] = total_mean + alpha * top_mean - beta * bm;
  }
}

extern "C" void kernel_launch(void* const* d_in, const int* in_sizes, int n_in,
                              void* d_out, int out_size, void* d_ws, size_t ws_size,
                              hipStream_t stream) {
  (void)in_sizes; (void)n_in; (void)out_size;
  const float* q_emb = (const float*)d_in[0];
  const float* p_emb = (const float*)d_in[1];
  const void* q_mask = d_in[2];
  const void* p_mask = d_in[3];
  const float* alpha_raw = (const float*)d_in[4];
  const float* beta_raw = (const float*)d_in[5];
  float* out = (float*)d_out;

  if (ws_size >= NEED_T) {
    unsigned char* qt = (unsigned char*)d_ws;
    unsigned char* pt = qt + (size_t)NA_G * 16;
    hipLaunchKernelGGL(convert_pack, dim3((NA_G + NB_G) / 256), dim3(256), 0, stream,
                       q_emb, p_emb, qt, pt);
    hipLaunchKernelGGL((dpr_fused<1>), dim3(2048), dim3(TB), 0, stream,
                       q_emb, p_emb, q_mask, p_mask, alpha_raw, beta_raw, qt, pt, out);
  } else {
    hipLaunchKernelGGL((dpr_fused<0>), dim3(2048), dim3(TB), 0, stream,
                       q_emb, p_emb, q_mask, p_mask, alpha_raw, beta_raw,
                       (const unsigned char*)nullptr, (const unsigned char*)nullptr, out);
  }
}

// Round 16
// 86.268 us; speedup vs baseline: 1.6461x; 1.6461x over previous
//
#include <hip/hip_runtime.h>

#define TB 256
#define NA_G (32 * 12 * 1024)   // 16B-groups in A tiles
#define NB_G (64 * 12 * 1024)   // 16B-groups in B tiles
#define NEED_T ((size_t)(NA_G + NB_G) * 16)          // 18.87 MB bf16 tiles

typedef __bf16 bf16x8 __attribute__((ext_vector_type(8)));
typedef float f32x4 __attribute__((ext_vector_type(4)));
typedef unsigned u32x4 __attribute__((ext_vector_type(4)));
typedef unsigned u32x2 __attribute__((ext_vector_type(2)));
typedef unsigned long long ull;

__device__ __forceinline__ unsigned pack2bf(float a, float b) {
  unsigned ua = __float_as_uint(a), ub = __float_as_uint(b);
  ua = (ua + 0x7fffu + ((ua >> 16) & 1u)) >> 16;   // RNE f32->bf16
  ub = (ub + 0x7fffu + ((ub >> 16) & 1u)) >> 16;
  return ua | (ub << 16);
}
__device__ __forceinline__ float bf2f(unsigned bits) {
  return __uint_as_float(bits << 16);
}
__device__ __forceinline__ void gll16(const void* g, void* l) {
  __builtin_amdgcn_global_load_lds(
      (const __attribute__((address_space(1))) unsigned*)g,
      (__attribute__((address_space(3))) unsigned*)l, 16, 0, 0);
}

// Pre-convert f32 -> bf16 into XOR-swizzled 128x64 tiles (LDS-image layout)
__global__ __launch_bounds__(256) void convert_pack(
    const float* __restrict__ q, const float* __restrict__ p,
    unsigned char* __restrict__ qt, unsigned char* __restrict__ pt) {
  int g = blockIdx.x * 256 + threadIdx.x;
  const float* src;
  unsigned char* dst;
  if (g < NA_G) { src = q; dst = qt; }
  else { g -= NA_G; src = p; dst = pt; }
  int tile = g >> 10;
  int o = (g & 1023) * 16;
  int row = o >> 7;
  int colb = (o & 127) ^ ((row & 7) << 4);
  int rb = tile / 12, kt = tile - rb * 12;
  const float* s = src + ((size_t)(rb * 128 + row)) * 768 + kt * 64 + (colb >> 1);
  float4 a = ((const float4*)s)[0];
  float4 b = ((const float4*)s)[1];
  uint4 w;
  w.x = pack2bf(a.x, a.y); w.y = pack2bf(a.z, a.w);
  w.z = pack2bf(b.x, b.y); w.w = pack2bf(b.z, b.w);
  *(uint4*)(dst + (size_t)tile * 16384 + o) = w;
}

// ===== fused: GEMM -> bf16 LDS handoff -> 2-pass fixed-point hist select =====
// R14 base. Selection: Pass A (min/max), Pass B (masked count + 16-bit
// fixed-point sum, INT atomics only), dual-carry scan; Pass C deleted.
// Hists alias the dead Sq quadrant (vv already in regs) -> LDS stays 32 KB.
// No dump bin (hot same-address atomics = R15 regression).
template <int PATH>
__global__ __launch_bounds__(TB, 4) void dpr_fused(
    const float* __restrict__ q_emb, const float* __restrict__ p_emb,
    const void* __restrict__ qmr, const void* __restrict__ pmr,
    const float* __restrict__ alpha_raw, const float* __restrict__ beta_raw,
    const unsigned char* __restrict__ qt, const unsigned char* __restrict__ pt,
    float* __restrict__ out) {
  __shared__ __align__(16) char arena[32768];  // GEMM: Al|Bl ; then 4x8KB S quadrants
  unsigned short* Al = (unsigned short*)arena;
  unsigned short* Bl = (unsigned short*)(arena + 16384);

  const int tid = threadIdx.x, lane = tid & 63, wid = tid >> 6;
  // XCD-clustered bid map: 8 regions of 16x16 block-tiles
  int g = blockIdx.x;
  int rg = g & 7, w = g >> 3;
  const int blockB = (rg >> 2) * 16 + (w & 15);
  const int blockP = (rg & 3) * 16 + (w >> 4);
  const int lr = lane & 15, lg = lane >> 4;
  const int db = wid >> 1, dp = wid & 1;

  // ---- per-wave masks (dtype sniffed) ----
  bool m32 = true;
  {
    const unsigned* qm32 = (const unsigned*)qmr;
    #pragma unroll
    for (int i = 0; i < 8; ++i) m32 = m32 && (qm32[i] <= 1u);
  }
  int qrow = (blockB * 2 + db) * 64 + lane;
  int pcolg = (blockP * 2 + dp) * 64 + lane;
  bool qvb = m32 ? (((const int*)qmr)[qrow] != 0) : (((const unsigned char*)qmr)[qrow] != 0);
  bool pvb = m32 ? (((const int*)pmr)[pcolg] != 0) : (((const unsigned char*)pmr)[pcolg] != 0);
  ull qb = __ballot(qvb);
  ull pb = __ballot(pvb);
  const int n_pair = __popcll(qb) * __popcll(pb);

  // ---- GEMM: 128x128 block tile, each wave owns one 64x64 pair ----
  f32x4 acc[4][4];
  #pragma unroll
  for (int m = 0; m < 4; ++m)
    #pragma unroll
    for (int n = 0; n < 4; ++n)
      acc[m][n] = f32x4{0.f, 0.f, 0.f, 0.f};

  const float* Abase = q_emb + (size_t)(blockB * 128) * 768;
  const float* Bbase = p_emb + (size_t)(blockP * 128) * 768;

  for (int kt = 0; kt < 12; ++kt) {
    if (PATH == 1) {
      const unsigned char* qtile = qt + ((size_t)(blockB * 12 + kt)) * 16384;
      const unsigned char* ptile = pt + ((size_t)(blockP * 12 + kt)) * 16384;
      #pragma unroll
      for (int c2 = 0; c2 < 4; ++c2) {
        int chunk = wid * 4 + c2;
        gll16(qtile + chunk * 1024 + lane * 16, (char*)Al + chunk * 1024);
        gll16(ptile + chunk * 1024 + lane * 16, (char*)Bl + chunk * 1024);
      }
    } else {
      const int k0 = kt * 64;
      #pragma unroll
      for (int it = 0; it < 4; ++it) {
        int gg = tid + 256 * it;
        int row = gg >> 3;
        int col = (gg & 7) * 8;
        int off = (row * 128 + col * 2) ^ ((row & 7) << 4);
        const float4* sA = (const float4*)(Abase + (size_t)row * 768 + k0 + col);
        float4 a0 = sA[0], a1 = sA[1];
        uint4 wv;
        wv.x = pack2bf(a0.x, a0.y); wv.y = pack2bf(a0.z, a0.w);
        wv.z = pack2bf(a1.x, a1.y); wv.w = pack2bf(a1.z, a1.w);
        *(uint4*)((char*)Al + off) = wv;
        const float4* sB = (const float4*)(Bbase + (size_t)row * 768 + k0 + col);
        float4 b0 = sB[0], b1 = sB[1];
        wv.x = pack2bf(b0.x, b0.y); wv.y = pack2bf(b0.z, b0.w);
        wv.z = pack2bf(b1.x, b1.y); wv.w = pack2bf(b1.z, b1.w);
        *(uint4*)((char*)Bl + off) = wv;
      }
    }
    __syncthreads();
    #pragma unroll
    for (int ks = 0; ks < 2; ++ks) {
      bf16x8 af[4], bfr[4];
      #pragma unroll
      for (int m = 0; m < 4; ++m) {
        int row = db * 64 + m * 16 + lr;
        int off = (row * 128 + ks * 64 + lg * 16) ^ ((row & 7) << 4);
        af[m] = *(const bf16x8*)((const char*)Al + off);
      }
      #pragma unroll
      for (int n = 0; n < 4; ++n) {
        int row = dp * 64 + n * 16 + lr;
        int off = (row * 128 + ks * 64 + lg * 16) ^ ((row & 7) << 4);
        bfr[n] = *(const bf16x8*)((const char*)Bl + off);
      }
      #pragma unroll
      for (int m = 0; m < 4; ++m)
        #pragma unroll
        for (int n = 0; n < 4; ++n)
          acc[m][n] = __builtin_amdgcn_mfma_f32_16x16x32_bf16(af[m], bfr[n], acc[m][n], 0, 0, 0);
    }
    __syncthreads();   // final barrier also fences arena reuse below
  }

  const int outIdx = (blockB * 2 + db) * 128 + (blockP * 2 + dp);
  if (n_pair == 0) {
    if (lane == 0) out[outIdx] = -1e9f;
    return;
  }

  // ---- handoff: pack acc -> wave-private 8KB LDS quadrant ----
  char* Sq = arena + wid * 8192;
  #pragma unroll
  for (int m = 0; m < 4; ++m)
    #pragma unroll
    for (int n = 0; n < 4; ++n) {
      int row = n * 16 + lr;
      int byte = row * 128 + m * 32 + lg * 8;
      int swz = byte ^ ((row & 7) << 4);
      u32x2 wv;
      wv.x = pack2bf(acc[m][n][0], acc[m][n][1]);
      wv.y = pack2bf(acc[m][n][2], acc[m][n][3]);
      *(u32x2*)(Sq + swz) = wv;
    }

  // read back 64 values/lane (same-wave LDS ops are in-order; no barrier)
  u32x4 vv[8];
  #pragma unroll
  for (int t = 0; t < 8; ++t) {
    int base = t * 1024 + lane * 16;
    vv[t] = *(const u32x4*)(Sq + (base ^ ((lane >> 3) << 4)));
  }

  // per-lane validity: element (t*8+jj) valid iff pm8 bit t && qm8 bit jj
  const unsigned qm8 = (unsigned)((qb >> ((lane & 7) * 8)) & 0xFFull);
  unsigned pm8 = 0;
  #pragma unroll
  for (int t = 0; t < 8; ++t)
    pm8 |= (unsigned)((pb >> (t * 8 + (lane >> 3))) & 1ull) << t;

  int ksel = 4 * n_pair / 10; if (ksel < 1) ksel = 1;
  int lsel = 2 * n_pair / 10; if (lsel < 1) lsel = 1;

  // hists alias the (now value-dead after Pass B) Sq quadrant; vv is in regs.
  unsigned* c1 = (unsigned*)Sq;            // cnt[256]
  unsigned* f1 = (unsigned*)(Sq + 1040);   // fix[256] (16B aligned)

  // Pass A: masked min / max (registers + shfl)
  float mn = INFINITY, mx = -INFINITY;
  #pragma unroll
  for (int t = 0; t < 8; ++t) {
    if ((pm8 >> t) & 1u) {
      #pragma unroll
      for (int jj = 0; jj < 8; ++jj) {
        if ((qm8 >> jj) & 1u) {
          unsigned u = vv[t][jj >> 1];
          unsigned bits = (jj & 1) ? (u >> 16) : (u & 0xFFFFu);
          float x = bf2f(bits);
          mn = fminf(mn, x); mx = fmaxf(mx, x);
        }
      }
    }
  }
  #pragma unroll
  for (int off = 1; off < 64; off <<= 1) {
    mn = fminf(mn, __shfl_xor(mn, off));
    mx = fmaxf(mx, __shfl_xor(mx, off));
  }

  float tsum, topS, botS;
  if (!(mx > mn)) {
    tsum = (float)n_pair * mn;        // all valid values identical
    topS = (float)ksel * mn;
    botS = (float)lsel * mn;
  } else {
    const float sc16 = 65535.0f / (mx - mn);
    const float inv16 = (mx - mn) * (1.0f / 65535.0f);

    // zero cnt+fix (same-wave in-order vs the vv reads above)
    ((uint4*)c1)[lane] = uint4{0u, 0u, 0u, 0u};
    ((uint4*)f1)[lane] = uint4{0u, 0u, 0u, 0u};

    // Pass B: masked atomics; bin = q>>8; int value-sum via q (fire&forget)
    #pragma unroll
    for (int t = 0; t < 8; ++t) {
      if ((pm8 >> t) & 1u) {
        #pragma unroll
        for (int jj = 0; jj < 8; ++jj) {
          if ((qm8 >> jj) & 1u) {
            unsigned u = vv[t][jj >> 1];
            unsigned bits = (jj & 1) ? (u >> 16) : (u & 0xFFFFu);
            float x = bf2f(bits);
            int q = (int)((x - mn) * sc16);
            q = q < 0 ? 0 : (q > 65535 ? 65535 : q);
            atomicAdd(&c1[q >> 8], 1u);
            atomicAdd(&f1[q >> 8], (unsigned)q);
          }
        }
      }
    }

    // dual-carry scan: lane owns bins [lane*4, lane*4+4)
    uint4 cq = ((const uint4*)c1)[lane];
    uint4 fq = ((const uint4*)f1)[lane];
    const unsigned cl0 = cq.x, cl1 = cq.y, cl2 = cq.z, cl3 = cq.w;
    const unsigned fl0 = fq.x, fl1 = fq.y, fl2 = fq.z, fl3 = fq.w;
    const unsigned lc = cl0 + cl1 + cl2 + cl3;
    const unsigned lf = fl0 + fl1 + fl2 + fl3;
    unsigned runC = lc, runF = lf;
    #pragma unroll
    for (int off = 1; off < 64; off <<= 1) {
      unsigned o = __shfl_down(runC, off);
      unsigned of = __shfl_down(runF, off);
      if (lane + off < 64) { runC += o; runF += of; }
    }
    const unsigned totC = __shfl(runC, 0);
    const unsigned totF = __shfl(runF, 0);
    tsum = (float)totF * inv16 + (float)totC * mn;   // totC == n_pair

    // top locate (suffix: high bins first), carrying fix-sum-above
    unsigned aboveC = runC - lc, aboveF = runF - lf;
    bool fT = ((unsigned)ksel > aboveC) && ((unsigned)ksel <= runC);
    int sbT_ = 0, RT_ = 0; unsigned saF_ = 0u;
    if (fT) {
      unsigned a = aboveC, af = aboveF;
      if ((unsigned)ksel <= a + cl3) { sbT_ = 3; RT_ = (int)((unsigned)ksel - a); saF_ = af; }
      else { a += cl3; af += fl3;
      if ((unsigned)ksel <= a + cl2) { sbT_ = 2; RT_ = (int)((unsigned)ksel - a); saF_ = af; }
      else { a += cl2; af += fl2;
      if ((unsigned)ksel <= a + cl1) { sbT_ = 1; RT_ = (int)((unsigned)ksel - a); saF_ = af; }
      else { a += cl1; af += fl1; sbT_ = 0; RT_ = (int)((unsigned)ksel - a); saF_ = af; } } }
      sbT_ += lane * 4;
    }
    ull fmT = __ballot(fT);
    int srcT = fmT ? (int)__builtin_ctzll(fmT) : 0;
    const int sbT = __shfl(sbT_, srcT);
    const int RT = __shfl(RT_, srcT);
    const unsigned saFT = __shfl(saF_, srcT);

    // bottom locate (prefix: low bins first), carrying fix-sum-below
    unsigned belowC = totC - runC, belowF = totF - runF;
    bool fB = ((unsigned)lsel > belowC) && ((unsigned)lsel <= belowC + lc);
    int sbB_ = 0, RB_ = 0; unsigned sbF_ = 0u;
    if (fB) {
      unsigned a = belowC, af = belowF;
      if ((unsigned)lsel <= a + cl0) { sbB_ = 0; RB_ = (int)((unsigned)lsel - a); sbF_ = af; }
      else { a += cl0; af += fl0;
      if ((unsigned)lsel <= a + cl1) { sbB_ = 1; RB_ = (int)((unsigned)lsel - a); sbF_ = af; }
      else { a += cl1; af += fl1;
      if ((unsigned)lsel <= a + cl2) { sbB_ = 2; RB_ = (int)((unsigned)lsel - a); sbF_ = af; }
      else { a += cl2; af += fl2; sbB_ = 3; RB_ = (int)((unsigned)lsel - a); sbF_ = af; } } }
      sbB_ += lane * 4;
    }
    ull fmB = __ballot(fB);
    int srcB = fmB ? (int)__builtin_ctzll(fmB) : 0;
    const int sbB = __shfl(sbB_, srcB);
    const int RB = __shfl(RB_, srcB);
    const unsigned sbFB = __shfl(sbF_, srcB);

    // rank-bin count+fix (uniform-address broadcast reads)
    const unsigned cT = c1[sbT], bFixT = f1[sbT];
    const unsigned cB = c1[sbB], bFixB = f1[sbB];

    // tail = bin fix-mean * rank-in-bin; convert fix -> value domain
    float topFix = (float)saFT + (float)bFixT * ((float)RT / (float)cT);
    float botFix = (float)sbFB + (float)bFixB * ((float)RB / (float)cB);
    topS = topFix * inv16 + (float)ksel * mn;
    botS = botFix * inv16 + (float)lsel * mn;
  }

  if (lane == 0) {
    float alpha = log1pf(expf(alpha_raw[0]));
    float beta = log1pf(expf(beta_raw[0]));
    float total_mean = tsum / (float)n_pair;
    float top_mean = topS / (float)ksel;
    float bm = fmaxf(0.0f, -(botS / (float)lsel));
    out[outIdx] = total_mean + alpha * top_mean - beta * bm;
  }
}

extern "C" void kernel_launch(void* const* d_in, const int* in_sizes, int n_in,
                              void* d_out, int out_size, void* d_ws, size_t ws_size,
                              hipStream_t stream) {
  (void)in_sizes; (void)n_in; (void)out_size;
  const float* q_emb = (const float*)d_in[0];
  const float* p_emb = (const float*)d_in[1];
  const void* q_mask = d_in[2];
  const void* p_mask = d_in[3];
  const float* alpha_raw = (const float*)d_in[4];
  const float* beta_raw = (const float*)d_in[5];
  float* out = (float*)d_out;

  if (ws_size >= NEED_T) {
    unsigned char* qt = (unsigned char*)d_ws;
    unsigned char* pt = qt + (size_t)NA_G * 16;
    hipLaunchKernelGGL(convert_pack, dim3((NA_G + NB_G) / 256), dim3(256), 0, stream,
                       q_emb, p_emb, qt, pt);
    hipLaunchKernelGGL((dpr_fused<1>), dim3(2048), dim3(TB), 0, stream,
                       q_emb, p_emb, q_mask, p_mask, alpha_raw, beta_raw, qt, pt, out);
  } else {
    hipLaunchKernelGGL((dpr_fused<0>), dim3(2048), dim3(TB), 0, stream,
                       q_emb, p_emb, q_mask, p_mask, alpha_raw, beta_raw,
                       (const unsigned char*)nullptr, (const unsigned char*)nullptr, out);
  }
}

// Round 17
// 82.733 us; speedup vs baseline: 1.7165x; 1.0427x over previous
//
#include <hip/hip_runtime.h>

#define TB 256
#define NA_G (32 * 12 * 1024)   // 16B-groups in A tiles
#define NB_G (64 * 12 * 1024)   // 16B-groups in B tiles
#define NEED_T ((size_t)(NA_G + NB_G) * 16)          // 18.87 MB bf16 tiles

typedef __bf16 bf16x8 __attribute__((ext_vector_type(8)));
typedef float f32x4 __attribute__((ext_vector_type(4)));
typedef unsigned u32x4 __attribute__((ext_vector_type(4)));
typedef unsigned u32x2 __attribute__((ext_vector_type(2)));
typedef unsigned long long ull;

__device__ __forceinline__ unsigned pack2bf(float a, float b) {
  unsigned ua = __float_as_uint(a), ub = __float_as_uint(b);
  ua = (ua + 0x7fffu + ((ua >> 16) & 1u)) >> 16;   // RNE f32->bf16
  ub = (ub + 0x7fffu + ((ub >> 16) & 1u)) >> 16;
  return ua | (ub << 16);
}
__device__ __forceinline__ float bf2f(unsigned bits) {
  return __uint_as_float(bits << 16);
}
__device__ __forceinline__ void gll16(const void* g, void* l) {
  __builtin_amdgcn_global_load_lds(
      (const __attribute__((address_space(1))) unsigned*)g,
      (__attribute__((address_space(3))) unsigned*)l, 16, 0, 0);
}

// Pre-convert f32 -> bf16 into XOR-swizzled 128x64 tiles (LDS-image layout)
__global__ __launch_bounds__(256) void convert_pack(
    const float* __restrict__ q, const float* __restrict__ p,
    unsigned char* __restrict__ qt, unsigned char* __restrict__ pt) {
  int g = blockIdx.x * 256 + threadIdx.x;
  const float* src;
  unsigned char* dst;
  if (g < NA_G) { src = q; dst = qt; }
  else { g -= NA_G; src = p; dst = pt; }
  int tile = g >> 10;
  int o = (g & 1023) * 16;
  int row = o >> 7;
  int colb = (o & 127) ^ ((row & 7) << 4);
  int rb = tile / 12, kt = tile - rb * 12;
  const float* s = src + ((size_t)(rb * 128 + row)) * 768 + kt * 64 + (colb >> 1);
  float4 a = ((const float4*)s)[0];
  float4 b = ((const float4*)s)[1];
  uint4 w;
  w.x = pack2bf(a.x, a.y); w.y = pack2bf(a.z, a.w);
  w.z = pack2bf(b.x, b.y); w.w = pack2bf(b.z, b.w);
  *(uint4*)(dst + (size_t)tile * 16384 + o) = w;
}

// ===== fused: GEMM -> bf16 LDS handoff -> 2-pass PACKED-hist select =====
// Pass B now does ONE int atomic/elem: word = (1<<20)|(q&255). Capacity:
// mx>mn => bins 0 and 255 both occupied => per-bin cnt<=4095<2^12 and
// low-sum<=4095*255<2^20. Per-bin fixsum = cnt*(bin*256)+lowsum, exact.
template <int PATH>
__global__ __launch_bounds__(TB, 4) void dpr_fused(
    const float* __restrict__ q_emb, const float* __restrict__ p_emb,
    const void* __restrict__ qmr, const void* __restrict__ pmr,
    const float* __restrict__ alpha_raw, const float* __restrict__ beta_raw,
    const unsigned char* __restrict__ qt, const unsigned char* __restrict__ pt,
    float* __restrict__ out) {
  __shared__ __align__(16) char arena[32768];  // GEMM: Al|Bl ; then 4x8KB S quadrants
  unsigned short* Al = (unsigned short*)arena;
  unsigned short* Bl = (unsigned short*)(arena + 16384);

  const int tid = threadIdx.x, lane = tid & 63, wid = tid >> 6;
  // XCD-clustered bid map: 8 regions of 16x16 block-tiles
  int g = blockIdx.x;
  int rg = g & 7, w = g >> 3;
  const int blockB = (rg >> 2) * 16 + (w & 15);
  const int blockP = (rg & 3) * 16 + (w >> 4);
  const int lr = lane & 15, lg = lane >> 4;
  const int db = wid >> 1, dp = wid & 1;

  // ---- per-wave masks (dtype sniffed) ----
  bool m32 = true;
  {
    const unsigned* qm32 = (const unsigned*)qmr;
    #pragma unroll
    for (int i = 0; i < 8; ++i) m32 = m32 && (qm32[i] <= 1u);
  }
  int qrow = (blockB * 2 + db) * 64 + lane;
  int pcolg = (blockP * 2 + dp) * 64 + lane;
  bool qvb = m32 ? (((const int*)qmr)[qrow] != 0) : (((const unsigned char*)qmr)[qrow] != 0);
  bool pvb = m32 ? (((const int*)pmr)[pcolg] != 0) : (((const unsigned char*)pmr)[pcolg] != 0);
  ull qb = __ballot(qvb);
  ull pb = __ballot(pvb);
  const int n_pair = __popcll(qb) * __popcll(pb);

  // ---- GEMM: 128x128 block tile, each wave owns one 64x64 pair ----
  f32x4 acc[4][4];
  #pragma unroll
  for (int m = 0; m < 4; ++m)
    #pragma unroll
    for (int n = 0; n < 4; ++n)
      acc[m][n] = f32x4{0.f, 0.f, 0.f, 0.f};

  const float* Abase = q_emb + (size_t)(blockB * 128) * 768;
  const float* Bbase = p_emb + (size_t)(blockP * 128) * 768;

  for (int kt = 0; kt < 12; ++kt) {
    if (PATH == 1) {
      const unsigned char* qtile = qt + ((size_t)(blockB * 12 + kt)) * 16384;
      const unsigned char* ptile = pt + ((size_t)(blockP * 12 + kt)) * 16384;
      #pragma unroll
      for (int c2 = 0; c2 < 4; ++c2) {
        int chunk = wid * 4 + c2;
        gll16(qtile + chunk * 1024 + lane * 16, (char*)Al + chunk * 1024);
        gll16(ptile + chunk * 1024 + lane * 16, (char*)Bl + chunk * 1024);
      }
    } else {
      const int k0 = kt * 64;
      #pragma unroll
      for (int it = 0; it < 4; ++it) {
        int gg = tid + 256 * it;
        int row = gg >> 3;
        int col = (gg & 7) * 8;
        int off = (row * 128 + col * 2) ^ ((row & 7) << 4);
        const float4* sA = (const float4*)(Abase + (size_t)row * 768 + k0 + col);
        float4 a0 = sA[0], a1 = sA[1];
        uint4 wv;
        wv.x = pack2bf(a0.x, a0.y); wv.y = pack2bf(a0.z, a0.w);
        wv.z = pack2bf(a1.x, a1.y); wv.w = pack2bf(a1.z, a1.w);
        *(uint4*)((char*)Al + off) = wv;
        const float4* sB = (const float4*)(Bbase + (size_t)row * 768 + k0 + col);
        float4 b0 = sB[0], b1 = sB[1];
        wv.x = pack2bf(b0.x, b0.y); wv.y = pack2bf(b0.z, b0.w);
        wv.z = pack2bf(b1.x, b1.y); wv.w = pack2bf(b1.z, b1.w);
        *(uint4*)((char*)Bl + off) = wv;
      }
    }
    __syncthreads();
    #pragma unroll
    for (int ks = 0; ks < 2; ++ks) {
      bf16x8 af[4], bfr[4];
      #pragma unroll
      for (int m = 0; m < 4; ++m) {
        int row = db * 64 + m * 16 + lr;
        int off = (row * 128 + ks * 64 + lg * 16) ^ ((row & 7) << 4);
        af[m] = *(const bf16x8*)((const char*)Al + off);
      }
      #pragma unroll
      for (int n = 0; n < 4; ++n) {
        int row = dp * 64 + n * 16 + lr;
        int off = (row * 128 + ks * 64 + lg * 16) ^ ((row & 7) << 4);
        bfr[n] = *(const bf16x8*)((const char*)Bl + off);
      }
      #pragma unroll
      for (int m = 0; m < 4; ++m)
        #pragma unroll
        for (int n = 0; n < 4; ++n)
          acc[m][n] = __builtin_amdgcn_mfma_f32_16x16x32_bf16(af[m], bfr[n], acc[m][n], 0, 0, 0);
    }
    __syncthreads();   // final barrier also fences arena reuse below
  }

  const int outIdx = (blockB * 2 + db) * 128 + (blockP * 2 + dp);
  if (n_pair == 0) {
    if (lane == 0) out[outIdx] = -1e9f;
    return;
  }

  // ---- handoff: pack acc -> wave-private 8KB LDS quadrant ----
  char* Sq = arena + wid * 8192;
  #pragma unroll
  for (int m = 0; m < 4; ++m)
    #pragma unroll
    for (int n = 0; n < 4; ++n) {
      int row = n * 16 + lr;
      int byte = row * 128 + m * 32 + lg * 8;
      int swz = byte ^ ((row & 7) << 4);
      u32x2 wv;
      wv.x = pack2bf(acc[m][n][0], acc[m][n][1]);
      wv.y = pack2bf(acc[m][n][2], acc[m][n][3]);
      *(u32x2*)(Sq + swz) = wv;
    }

  // read back 64 values/lane (same-wave LDS ops are in-order; no barrier)
  u32x4 vv[8];
  #pragma unroll
  for (int t = 0; t < 8; ++t) {
    int base = t * 1024 + lane * 16;
    vv[t] = *(const u32x4*)(Sq + (base ^ ((lane >> 3) << 4)));
  }

  // per-lane validity: element (t*8+jj) valid iff pm8 bit t && qm8 bit jj
  const unsigned qm8 = (unsigned)((qb >> ((lane & 7) * 8)) & 0xFFull);
  unsigned pm8 = 0;
  #pragma unroll
  for (int t = 0; t < 8; ++t)
    pm8 |= (unsigned)((pb >> (t * 8 + (lane >> 3))) & 1ull) << t;

  int ksel = 4 * n_pair / 10; if (ksel < 1) ksel = 1;
  int lsel = 2 * n_pair / 10; if (lsel < 1) lsel = 1;

  // packed hist aliases the (value-dead after readback) Sq quadrant
  unsigned* c1 = (unsigned*)Sq;   // 256 x packed {cnt:12 | lowsum:20}

  // Pass A: masked min / max (registers + shfl)
  float mn = INFINITY, mx = -INFINITY;
  #pragma unroll
  for (int t = 0; t < 8; ++t) {
    if ((pm8 >> t) & 1u) {
      #pragma unroll
      for (int jj = 0; jj < 8; ++jj) {
        if ((qm8 >> jj) & 1u) {
          unsigned u = vv[t][jj >> 1];
          unsigned bits = (jj & 1) ? (u >> 16) : (u & 0xFFFFu);
          float x = bf2f(bits);
          mn = fminf(mn, x); mx = fmaxf(mx, x);
        }
      }
    }
  }
  #pragma unroll
  for (int off = 1; off < 64; off <<= 1) {
    mn = fminf(mn, __shfl_xor(mn, off));
    mx = fmaxf(mx, __shfl_xor(mx, off));
  }

  float tsum, topS, botS;
  if (!(mx > mn)) {
    tsum = (float)n_pair * mn;        // all valid values identical
    topS = (float)ksel * mn;
    botS = (float)lsel * mn;
  } else {
    const float sc16 = 65535.0f / (mx - mn);
    const float inv16 = (mx - mn) * (1.0f / 65535.0f);

    // zero hist (same-wave in-order vs the vv reads above)
    ((uint4*)c1)[lane] = uint4{0u, 0u, 0u, 0u};

    // Pass B: ONE masked packed atomic per element
    #pragma unroll
    for (int t = 0; t < 8; ++t) {
      if ((pm8 >> t) & 1u) {
        #pragma unroll
        for (int jj = 0; jj < 8; ++jj) {
          if ((qm8 >> jj) & 1u) {
            unsigned u = vv[t][jj >> 1];
            unsigned bits = (jj & 1) ? (u >> 16) : (u & 0xFFFFu);
            float x = bf2f(bits);
            int q = (int)((x - mn) * sc16);
            q = q < 0 ? 0 : (q > 65535 ? 65535 : q);
            atomicAdd(&c1[q >> 8], (1u << 20) | (unsigned)(q & 255));
          }
        }
      }
    }

    // unpack lane's 4 bins; reconstruct exact per-bin fixsum
    uint4 wq = ((const uint4*)c1)[lane];
    const unsigned cl0 = wq.x >> 20, cl1 = wq.y >> 20, cl2 = wq.z >> 20, cl3 = wq.w >> 20;
    const int b0i = lane * 4;
    const unsigned fl0 = (wq.x & 0xFFFFFu) + cl0 * ((unsigned)(b0i + 0) << 8);
    const unsigned fl1 = (wq.y & 0xFFFFFu) + cl1 * ((unsigned)(b0i + 1) << 8);
    const unsigned fl2 = (wq.z & 0xFFFFFu) + cl2 * ((unsigned)(b0i + 2) << 8);
    const unsigned fl3 = (wq.w & 0xFFFFFu) + cl3 * ((unsigned)(b0i + 3) << 8);
    const unsigned lc = cl0 + cl1 + cl2 + cl3;
    const unsigned lf = fl0 + fl1 + fl2 + fl3;
    unsigned runC = lc, runF = lf;
    #pragma unroll
    for (int off = 1; off < 64; off <<= 1) {
      unsigned o = __shfl_down(runC, off);
      unsigned of = __shfl_down(runF, off);
      if (lane + off < 64) { runC += o; runF += of; }
    }
    const unsigned totC = __shfl(runC, 0);
    const unsigned totF = __shfl(runF, 0);
    tsum = (float)totF * inv16 + (float)totC * mn;   // totC == n_pair

    // top locate (suffix: high bins first), carrying fix-sum-above
    unsigned aboveC = runC - lc, aboveF = runF - lf;
    bool fT = ((unsigned)ksel > aboveC) && ((unsigned)ksel <= runC);
    int sbT_ = 0, RT_ = 0; unsigned saF_ = 0u, bcT_ = 0u, bfT_ = 0u;
    if (fT) {
      unsigned a = aboveC, af = aboveF;
      if ((unsigned)ksel <= a + cl3) { sbT_ = 3; RT_ = (int)((unsigned)ksel - a); saF_ = af; bcT_ = cl3; bfT_ = fl3; }
      else { a += cl3; af += fl3;
      if ((unsigned)ksel <= a + cl2) { sbT_ = 2; RT_ = (int)((unsigned)ksel - a); saF_ = af; bcT_ = cl2; bfT_ = fl2; }
      else { a += cl2; af += fl2;
      if ((unsigned)ksel <= a + cl1) { sbT_ = 1; RT_ = (int)((unsigned)ksel - a); saF_ = af; bcT_ = cl1; bfT_ = fl1; }
      else { a += cl1; af += fl1; sbT_ = 0; RT_ = (int)((unsigned)ksel - a); saF_ = af; bcT_ = cl0; bfT_ = fl0; } } }
    }
    ull fmT = __ballot(fT);
    int srcT = fmT ? (int)__builtin_ctzll(fmT) : 0;
    const int RT = __shfl(RT_, srcT);
    const unsigned saFT = __shfl(saF_, srcT);
    const unsigned cT = __shfl(bcT_, srcT);
    const unsigned bFixT = __shfl(bfT_, srcT);

    // bottom locate (prefix: low bins first), carrying fix-sum-below
    unsigned belowC = totC - runC, belowF = totF - runF;
    bool fB = ((unsigned)lsel > belowC) && ((unsigned)lsel <= belowC + lc);
    int RB_ = 0; unsigned sbF_ = 0u, bcB_ = 0u, bfB_ = 0u;
    if (fB) {
      unsigned a = belowC, af = belowF;
      if ((unsigned)lsel <= a + cl0) { RB_ = (int)((unsigned)lsel - a); sbF_ = af; bcB_ = cl0; bfB_ = fl0; }
      else { a += cl0; af += fl0;
      if ((unsigned)lsel <= a + cl1) { RB_ = (int)((unsigned)lsel - a); sbF_ = af; bcB_ = cl1; bfB_ = fl1; }
      else { a += cl1; af += fl1;
      if ((unsigned)lsel <= a + cl2) { RB_ = (int)((unsigned)lsel - a); sbF_ = af; bcB_ = cl2; bfB_ = fl2; }
      else { a += cl2; af += fl2; RB_ = (int)((unsigned)lsel - a); sbF_ = af; bcB_ = cl3; bfB_ = fl3; } } }
    }
    ull fmB = __ballot(fB);
    int srcB = fmB ? (int)__builtin_ctzll(fmB) : 0;
    const int RB = __shfl(RB_, srcB);
    const unsigned sbFB = __shfl(sbF_, srcB);
    const unsigned cB = __shfl(bcB_, srcB);
    const unsigned bFixB = __shfl(bfB_, srcB);

    // tail = bin fix-mean * rank-in-bin; convert fix -> value domain
    float topFix = (float)saFT + (float)bFixT * ((float)RT / (float)cT);
    float botFix = (float)sbFB + (float)bFixB * ((float)RB / (float)cB);
    topS = topFix * inv16 + (float)ksel * mn;
    botS = botFix * inv16 + (float)lsel * mn;
  }

  if (lane == 0) {
    float alpha = log1pf(expf(alpha_raw[0]));
    float beta = log1pf(expf(beta_raw[0]));
    float total_mean = tsum / (float)n_pair;
    float top_mean = topS / (float)ksel;
    float bm = fmaxf(0.0f, -(botS / (float)lsel));
    out[outIdx] = total_mean + alpha * top_mean - beta * bm;
  }
}

extern "C" void kernel_launch(void* const* d_in, const int* in_sizes, int n_in,
                              void* d_out, int out_size, void* d_ws, size_t ws_size,
                              hipStream_t stream) {
  (void)in_sizes; (void)n_in; (void)out_size;
  const float* q_emb = (const float*)d_in[0];
  const float* p_emb = (const float*)d_in[1];
  const void* q_mask = d_in[2];
  const void* p_mask = d_in[3];
  const float* alpha_raw = (const float*)d_in[4];
  const float* beta_raw = (const float*)d_in[5];
  float* out = (float*)d_out;

  if (ws_size >= NEED_T) {
    unsigned char* qt = (unsigned char*)d_ws;
    unsigned char* pt = qt + (size_t)NA_G * 16;
    hipLaunchKernelGGL(convert_pack, dim3((NA_G + NB_G) / 256), dim3(256), 0, stream,
                       q_emb, p_emb, qt, pt);
    hipLaunchKernelGGL((dpr_fused<1>), dim3(2048), dim3(TB), 0, stream,
                       q_emb, p_emb, q_mask, p_mask, alpha_raw, beta_raw, qt, pt, out);
  } else {
    hipLaunchKernelGGL((dpr_fused<0>), dim3(2048), dim3(TB), 0, stream,
                       q_emb, p_emb, q_mask, p_mask, alpha_raw, beta_raw,
                       (const unsigned char*)nullptr, (const unsigned char*)nullptr, out);
  }
}

// Round 18
// 81.504 us; speedup vs baseline: 1.7424x; 1.0151x over previous
//
#include <hip/hip_runtime.h>

#define TB 256
#define NA_G (32 * 12 * 1024)   // 16B-groups in A tiles
#define NB_G (64 * 12 * 1024)   // 16B-groups in B tiles
#define NEED_T ((size_t)(NA_G + NB_G) * 16)          // 18.87 MB bf16 tiles

typedef __bf16 bf16x8 __attribute__((ext_vector_type(8)));
typedef float f32x4 __attribute__((ext_vector_type(4)));
typedef unsigned long long ull;

__device__ __forceinline__ unsigned pack2bf(float a, float b) {
  unsigned ua = __float_as_uint(a), ub = __float_as_uint(b);
  ua = (ua + 0x7fffu + ((ua >> 16) & 1u)) >> 16;   // RNE f32->bf16
  ub = (ub + 0x7fffu + ((ub >> 16) & 1u)) >> 16;
  return ua | (ub << 16);
}
__device__ __forceinline__ void gll16(const void* g, void* l) {
  __builtin_amdgcn_global_load_lds(
      (const __attribute__((address_space(1))) unsigned*)g,
      (__attribute__((address_space(3))) unsigned*)l, 16, 0, 0);
}

// Pre-convert f32 -> bf16 into XOR-swizzled 128x64 tiles (LDS-image layout)
__global__ __launch_bounds__(256) void convert_pack(
    const float* __restrict__ q, const float* __restrict__ p,
    unsigned char* __restrict__ qt, unsigned char* __restrict__ pt) {
  int g = blockIdx.x * 256 + threadIdx.x;
  const float* src;
  unsigned char* dst;
  if (g < NA_G) { src = q; dst = qt; }
  else { g -= NA_G; src = p; dst = pt; }
  int tile = g >> 10;
  int o = (g & 1023) * 16;
  int row = o >> 7;
  int colb = (o & 127) ^ ((row & 7) << 4);
  int rb = tile / 12, kt = tile - rb * 12;
  const float* s = src + ((size_t)(rb * 128 + row)) * 768 + kt * 64 + (colb >> 1);
  float4 a = ((const float4*)s)[0];
  float4 b = ((const float4*)s)[1];
  uint4 w;
  w.x = pack2bf(a.x, a.y); w.y = pack2bf(a.z, a.w);
  w.z = pack2bf(b.x, b.y); w.w = pack2bf(b.z, b.w);
  *(uint4*)(dst + (size_t)tile * 16384 + o) = w;
}

// ===== fused: GEMM -> acc-direct 2-pass PACKED-hist select (no handoff) =====
// Selection runs straight on the AGPR accumulators: Pass A (masked min/max),
// Pass B (masked quantize + ONE packed int atomic: (1<<20)|(q&255)).
// Capacity: mx>mn => bins 0,255 occupied => cnt<=4095<2^12, lowsum<2^20.
// Per-bin fixsum = cnt*(bin*256)+lowsum, exact in quantized domain.
// R13's spill is avoided because selection temps are ~20 VGPR (no bpk/ull
// masks/Pass C); float LDS atomics remain banned (CAS-loop, R10/R11).
template <int PATH>
__global__ __launch_bounds__(TB, 4) void dpr_fused(
    const float* __restrict__ q_emb, const float* __restrict__ p_emb,
    const void* __restrict__ qmr, const void* __restrict__ pmr,
    const float* __restrict__ alpha_raw, const float* __restrict__ beta_raw,
    const unsigned char* __restrict__ qt, const unsigned char* __restrict__ pt,
    float* __restrict__ out) {
  __shared__ __align__(16) char arena[32768];  // GEMM: Al|Bl ; then 1KB hist/wave
  unsigned short* Al = (unsigned short*)arena;
  unsigned short* Bl = (unsigned short*)(arena + 16384);

  const int tid = threadIdx.x, lane = tid & 63, wid = tid >> 6;
  // XCD-clustered bid map: 8 regions of 16x16 block-tiles
  int g = blockIdx.x;
  int rg = g & 7, w = g >> 3;
  const int blockB = (rg >> 2) * 16 + (w & 15);
  const int blockP = (rg & 3) * 16 + (w >> 4);
  const int lr = lane & 15, lg = lane >> 4;
  const int db = wid >> 1, dp = wid & 1;

  // ---- per-wave masks (dtype sniffed) ----
  bool m32 = true;
  {
    const unsigned* qm32 = (const unsigned*)qmr;
    #pragma unroll
    for (int i = 0; i < 8; ++i) m32 = m32 && (qm32[i] <= 1u);
  }
  int qrow = (blockB * 2 + db) * 64 + lane;
  int pcolg = (blockP * 2 + dp) * 64 + lane;
  bool qvb = m32 ? (((const int*)qmr)[qrow] != 0) : (((const unsigned char*)qmr)[qrow] != 0);
  bool pvb = m32 ? (((const int*)pmr)[pcolg] != 0) : (((const unsigned char*)pmr)[pcolg] != 0);
  ull qb = __ballot(qvb);
  ull pb = __ballot(pvb);
  const int n_pair = __popcll(qb) * __popcll(pb);

  // ---- GEMM: 128x128 block tile, each wave owns one 64x64 pair ----
  f32x4 acc[4][4];
  #pragma unroll
  for (int m = 0; m < 4; ++m)
    #pragma unroll
    for (int n = 0; n < 4; ++n)
      acc[m][n] = f32x4{0.f, 0.f, 0.f, 0.f};

  const float* Abase = q_emb + (size_t)(blockB * 128) * 768;
  const float* Bbase = p_emb + (size_t)(blockP * 128) * 768;

  for (int kt = 0; kt < 12; ++kt) {
    if (PATH == 1) {
      const unsigned char* qtile = qt + ((size_t)(blockB * 12 + kt)) * 16384;
      const unsigned char* ptile = pt + ((size_t)(blockP * 12 + kt)) * 16384;
      #pragma unroll
      for (int c2 = 0; c2 < 4; ++c2) {
        int chunk = wid * 4 + c2;
        gll16(qtile + chunk * 1024 + lane * 16, (char*)Al + chunk * 1024);
        gll16(ptile + chunk * 1024 + lane * 16, (char*)Bl + chunk * 1024);
      }
    } else {
      const int k0 = kt * 64;
      #pragma unroll
      for (int it = 0; it < 4; ++it) {
        int gg = tid + 256 * it;
        int row = gg >> 3;
        int col = (gg & 7) * 8;
        int off = (row * 128 + col * 2) ^ ((row & 7) << 4);
        const float4* sA = (const float4*)(Abase + (size_t)row * 768 + k0 + col);
        float4 a0 = sA[0], a1 = sA[1];
        uint4 wv;
        wv.x = pack2bf(a0.x, a0.y); wv.y = pack2bf(a0.z, a0.w);
        wv.z = pack2bf(a1.x, a1.y); wv.w = pack2bf(a1.z, a1.w);
        *(uint4*)((char*)Al + off) = wv;
        const float4* sB = (const float4*)(Bbase + (size_t)row * 768 + k0 + col);
        float4 b0 = sB[0], b1 = sB[1];
        wv.x = pack2bf(b0.x, b0.y); wv.y = pack2bf(b0.z, b0.w);
        wv.z = pack2bf(b1.x, b1.y); wv.w = pack2bf(b1.z, b1.w);
        *(uint4*)((char*)Bl + off) = wv;
      }
    }
    __syncthreads();
    #pragma unroll
    for (int ks = 0; ks < 2; ++ks) {
      bf16x8 af[4], bfr[4];
      #pragma unroll
      for (int m = 0; m < 4; ++m) {
        int row = db * 64 + m * 16 + lr;
        int off = (row * 128 + ks * 64 + lg * 16) ^ ((row & 7) << 4);
        af[m] = *(const bf16x8*)((const char*)Al + off);
      }
      #pragma unroll
      for (int n = 0; n < 4; ++n) {
        int row = dp * 64 + n * 16 + lr;
        int off = (row * 128 + ks * 64 + lg * 16) ^ ((row & 7) << 4);
        bfr[n] = *(const bf16x8*)((const char*)Bl + off);
      }
      #pragma unroll
      for (int m = 0; m < 4; ++m)
        #pragma unroll
        for (int n = 0; n < 4; ++n)
          acc[m][n] = __builtin_amdgcn_mfma_f32_16x16x32_bf16(af[m], bfr[n], acc[m][n], 0, 0, 0);
    }
    __syncthreads();   // final barrier also fences arena reuse below
  }

  const int outIdx = (blockB * 2 + db) * 128 + (blockP * 2 + dp);
  if (n_pair == 0) {
    if (lane == 0) out[outIdx] = -1e9f;
    return;
  }

  // per-lane validity of the 64 owned elements (idx=(m*4+n)*4+j)
  unsigned vlo = 0, vhi = 0;
  {
    unsigned qn[4], pc[4];
    #pragma unroll
    for (int m = 0; m < 4; ++m) qn[m] = (unsigned)((qb >> (m * 16 + lg * 4)) & 0xFull);
    #pragma unroll
    for (int n = 0; n < 4; ++n) pc[n] = ((pb >> (n * 16 + lr)) & 1ull) ? 0xFu : 0u;
    #pragma unroll
    for (int m = 0; m < 2; ++m)
      #pragma unroll
      for (int n = 0; n < 4; ++n) vlo |= (qn[m] & pc[n]) << ((m * 4 + n) * 4);
    #pragma unroll
    for (int m = 2; m < 4; ++m)
      #pragma unroll
      for (int n = 0; n < 4; ++n) vhi |= (qn[m] & pc[n]) << (((m - 2) * 4 + n) * 4);
  }
  #define VBIT(idx) ((idx) < 32 ? ((vlo >> (idx)) & 1u) : ((vhi >> ((idx) - 32)) & 1u))

  int ksel = 4 * n_pair / 10; if (ksel < 1) ksel = 1;
  int lsel = 2 * n_pair / 10; if (lsel < 1) lsel = 1;

  // packed hist aliases the dead arena; wave-private 1KB
  unsigned* c1 = (unsigned*)(arena + wid * 8192);

  // Pass A: masked min / max over acc (registers + shfl)
  float mn = INFINITY, mx = -INFINITY;
  #pragma unroll
  for (int m = 0; m < 4; ++m)
    #pragma unroll
    for (int n = 0; n < 4; ++n)
      #pragma unroll
      for (int j = 0; j < 4; ++j) {
        const int idx = (m * 4 + n) * 4 + j;
        float x = acc[m][n][j];
        if (VBIT(idx)) { mn = fminf(mn, x); mx = fmaxf(mx, x); }
      }
  #pragma unroll
  for (int off = 1; off < 64; off <<= 1) {
    mn = fminf(mn, __shfl_xor(mn, off));
    mx = fmaxf(mx, __shfl_xor(mx, off));
  }

  float tsum, topS, botS;
  if (!(mx > mn)) {
    tsum = (float)n_pair * mn;        // all valid values identical
    topS = (float)ksel * mn;
    botS = (float)lsel * mn;
  } else {
    const float sc16 = 65535.0f / (mx - mn);
    const float inv16 = (mx - mn) * (1.0f / 65535.0f);

    // zero hist (same-wave in-order)
    ((uint4*)c1)[lane] = uint4{0u, 0u, 0u, 0u};

    // Pass B: ONE masked packed atomic per acc element
    #pragma unroll
    for (int m = 0; m < 4; ++m)
      #pragma unroll
      for (int n = 0; n < 4; ++n)
        #pragma unroll
        for (int j = 0; j < 4; ++j) {
          const int idx = (m * 4 + n) * 4 + j;
          if (VBIT(idx)) {
            int q = (int)((acc[m][n][j] - mn) * sc16);
            q = q < 0 ? 0 : (q > 65535 ? 65535 : q);
            atomicAdd(&c1[q >> 8], (1u << 20) | (unsigned)(q & 255));
          }
        }

    // unpack lane's 4 bins; reconstruct exact per-bin fixsum
    uint4 wq = ((const uint4*)c1)[lane];
    const unsigned cl0 = wq.x >> 20, cl1 = wq.y >> 20, cl2 = wq.z >> 20, cl3 = wq.w >> 20;
    const int b0i = lane * 4;
    const unsigned fl0 = (wq.x & 0xFFFFFu) + cl0 * ((unsigned)(b0i + 0) << 8);
    const unsigned fl1 = (wq.y & 0xFFFFFu) + cl1 * ((unsigned)(b0i + 1) << 8);
    const unsigned fl2 = (wq.z & 0xFFFFFu) + cl2 * ((unsigned)(b0i + 2) << 8);
    const unsigned fl3 = (wq.w & 0xFFFFFu) + cl3 * ((unsigned)(b0i + 3) << 8);
    const unsigned lc = cl0 + cl1 + cl2 + cl3;
    const unsigned lf = fl0 + fl1 + fl2 + fl3;
    unsigned runC = lc, runF = lf;
    #pragma unroll
    for (int off = 1; off < 64; off <<= 1) {
      unsigned o = __shfl_down(runC, off);
      unsigned of = __shfl_down(runF, off);
      if (lane + off < 64) { runC += o; runF += of; }
    }
    const unsigned totC = __shfl(runC, 0);
    const unsigned totF = __shfl(runF, 0);
    tsum = (float)totF * inv16 + (float)totC * mn;   // totC == n_pair

    // top locate (suffix: high bins first), carrying fix-sum-above
    unsigned aboveC = runC - lc, aboveF = runF - lf;
    bool fT = ((unsigned)ksel > aboveC) && ((unsigned)ksel <= runC);
    int RT_ = 0; unsigned saF_ = 0u, bcT_ = 0u, bfT_ = 0u;
    if (fT) {
      unsigned a = aboveC, af = aboveF;
      if ((unsigned)ksel <= a + cl3) { RT_ = (int)((unsigned)ksel - a); saF_ = af; bcT_ = cl3; bfT_ = fl3; }
      else { a += cl3; af += fl3;
      if ((unsigned)ksel <= a + cl2) { RT_ = (int)((unsigned)ksel - a); saF_ = af; bcT_ = cl2; bfT_ = fl2; }
      else { a += cl2; af += fl2;
      if ((unsigned)ksel <= a + cl1) { RT_ = (int)((unsigned)ksel - a); saF_ = af; bcT_ = cl1; bfT_ = fl1; }
      else { a += cl1; af += fl1; RT_ = (int)((unsigned)ksel - a); saF_ = af; bcT_ = cl0; bfT_ = fl0; } } }
    }
    ull fmT = __ballot(fT);
    int srcT = fmT ? (int)__builtin_ctzll(fmT) : 0;
    const int RT = __shfl(RT_, srcT);
    const unsigned saFT = __shfl(saF_, srcT);
    const unsigned cT = __shfl(bcT_, srcT);
    const unsigned bFixT = __shfl(bfT_, srcT);

    // bottom locate (prefix: low bins first), carrying fix-sum-below
    unsigned belowC = totC - runC, belowF = totF - runF;
    bool fB = ((unsigned)lsel > belowC) && ((unsigned)lsel <= belowC + lc);
    int RB_ = 0; unsigned sbF_ = 0u, bcB_ = 0u, bfB_ = 0u;
    if (fB) {
      unsigned a = belowC, af = belowF;
      if ((unsigned)lsel <= a + cl0) { RB_ = (int)((unsigned)lsel - a); sbF_ = af; bcB_ = cl0; bfB_ = fl0; }
      else { a += cl0; af += fl0;
      if ((unsigned)lsel <= a + cl1) { RB_ = (int)((unsigned)lsel - a); sbF_ = af; bcB_ = cl1; bfB_ = fl1; }
      else { a += cl1; af += fl1;
      if ((unsigned)lsel <= a + cl2) { RB_ = (int)((unsigned)lsel - a); sbF_ = af; bcB_ = cl2; bfB_ = fl2; }
      else { a += cl2; af += fl2; RB_ = (int)((unsigned)lsel - a); sbF_ = af; bcB_ = cl3; bfB_ = fl3; } } }
    }
    ull fmB = __ballot(fB);
    int srcB = fmB ? (int)__builtin_ctzll(fmB) : 0;
    const int RB = __shfl(RB_, srcB);
    const unsigned sbFB = __shfl(sbF_, srcB);
    const unsigned cB = __shfl(bcB_, srcB);
    const unsigned bFixB = __shfl(bfB_, srcB);

    // tail = bin fix-mean * rank-in-bin; convert fix -> value domain
    float topFix = (float)saFT + (float)bFixT * ((float)RT / (float)cT);
    float botFix = (float)sbFB + (float)bFixB * ((float)RB / (float)cB);
    topS = topFix * inv16 + (float)ksel * mn;
    botS = botFix * inv16 + (float)lsel * mn;
  }
  #undef VBIT

  if (lane == 0) {
    float alpha = log1pf(expf(alpha_raw[0]));
    float beta = log1pf(expf(beta_raw[0]));
    float total_mean = tsum / (float)n_pair;
    float top_mean = topS / (float)ksel;
    float bm = fmaxf(0.0f, -(botS / (float)lsel));
    out[outIdx] = total_mean + alpha * top_mean - beta * bm;
  }
}

extern "C" void kernel_launch(void* const* d_in, const int* in_sizes, int n_in,
                              void* d_out, int out_size, void* d_ws, size_t ws_size,
                              hipStream_t stream) {
  (void)in_sizes; (void)n_in; (void)out_size;
  const float* q_emb = (const float*)d_in[0];
  const float* p_emb = (const float*)d_in[1];
  const void* q_mask = d_in[2];
  const void* p_mask = d_in[3];
  const float* alpha_raw = (const float*)d_in[4];
  const float* beta_raw = (const float*)d_in[5];
  float* out = (float*)d_out;

  if (ws_size >= NEED_T) {
    unsigned char* qt = (unsigned char*)d_ws;
    unsigned char* pt = qt + (size_t)NA_G * 16;
    hipLaunchKernelGGL(convert_pack, dim3((NA_G + NB_G) / 256), dim3(256), 0, stream,
                       q_emb, p_emb, qt, pt);
    hipLaunchKernelGGL((dpr_fused<1>), dim3(2048), dim3(TB), 0, stream,
                       q_emb, p_emb, q_mask, p_mask, alpha_raw, beta_raw, qt, pt, out);
  } else {
    hipLaunchKernelGGL((dpr_fused<0>), dim3(2048), dim3(TB), 0, stream,
                       q_emb, p_emb, q_mask, p_mask, alpha_raw, beta_raw,
                       (const unsigned char*)nullptr, (const unsigned char*)nullptr, out);
  }
}